// Round 7
// baseline (250.785 us; speedup 1.0000x reference)
//
#include <hip/hip_runtime.h>
#include <hip/hip_bf16.h>

#define B_ 4
#define S_ 2048
#define D_ 1024
#define H_ 16
#define DK_ 64

typedef __attribute__((ext_vector_type(8))) short bf16x8;
typedef __attribute__((ext_vector_type(4))) float f32x4;
typedef __attribute__((ext_vector_type(4))) unsigned int u32x4;

__device__ __forceinline__ unsigned short f2bf(float f) {
    unsigned int u = __float_as_uint(f);
    u += 0x7FFFu + ((u >> 16) & 1u);
    return (unsigned short)(u >> 16);
}

__device__ __forceinline__ unsigned int cvtpk_bf16(float lo, float hi) {
    unsigned int r;
    asm("v_cvt_pk_bf16_f32 %0, %1, %2" : "=v"(r) : "v"(lo), "v"(hi));
    return r;
}

#define BAR() do { __builtin_amdgcn_s_barrier(); asm volatile("" ::: "memory"); } while (0)

// ---- fp32 -> bf16 bulk convert (n multiple of 2048) ----
__global__ void cvt_kernel(const float* __restrict__ src, unsigned short* __restrict__ dst) {
    int i = (blockIdx.x * 256 + threadIdx.x) * 8;
    float4 f0 = *(const float4*)&src[i];
    float4 f1 = *(const float4*)&src[i + 4];
    unsigned short t[8] __attribute__((aligned(16))) = {
        f2bf(f0.x), f2bf(f0.y), f2bf(f0.z), f2bf(f0.w),
        f2bf(f1.x), f2bf(f1.y), f2bf(f1.z), f2bf(f1.w)};
    *(u32x4*)&dst[i] = *(const u32x4*)t;
}

// ---- prepack: Wq/Wk/Wv fp32 [H][D][DK] -> bf16 Wt [3*H*DK][D] via LDS transpose ----
// Wq is pre-scaled by log2(e)/8 so attention scores come out of QK^T ready for exp2.
__global__ void prepack_kernel(const float* __restrict__ Wq,
                               const float* __restrict__ Wk,
                               const float* __restrict__ Wv,
                               unsigned short* __restrict__ Wt) {
    __shared__ unsigned short Ts[64 * 65];
    int h = blockIdx.x, w3 = blockIdx.y, t = blockIdx.z;
    const float* src = (w3 == 0 ? Wq : (w3 == 1 ? Wk : Wv)) + h * D_ * DK_ + t * 64 * DK_;
    unsigned short* dst = Wt + (w3 * H_ + h) * DK_ * D_ + t * 64;
    const float wscale = (w3 == 0) ? 0.18033688011112042f : 1.0f;  // (1/sqrt(64)) * log2(e)
    int tid = threadIdx.x;
    for (int rep = 0; rep < 16; ++rep) {
        int idx = rep * 256 + tid;
        int dl = idx >> 6, k = idx & 63;
        Ts[k * 65 + dl] = f2bf(src[dl * 64 + k] * wscale);
    }
    __syncthreads();
    for (int rep = 0; rep < 16; ++rep) {
        int idx = rep * 256 + tid;
        int kl = idx >> 6, dl = idx & 63;
        dst[kl * D_ + dl] = Ts[kl * 65 + dl];
    }
}

// ---- merged prep: cvt(x) [4096 blocks] + cvt(Wo) [512 blocks] + prepack [768 blocks] ----
__global__ __launch_bounds__(256) void prep_kernel(const float* __restrict__ x,
                                                   const float* __restrict__ Wq,
                                                   const float* __restrict__ Wk,
                                                   const float* __restrict__ Wv,
                                                   const float* __restrict__ Wo,
                                                   unsigned short* __restrict__ xbf,
                                                   unsigned short* __restrict__ Wt,
                                                   unsigned short* __restrict__ Wobf) {
    __shared__ unsigned short Ts[64 * 65];
    const int bid = blockIdx.x;
    const int tid = threadIdx.x;
    if (bid < 4096 + 512) {
        const bool isx = bid < 4096;
        const float* src = isx ? x : Wo;
        unsigned short* dst = isx ? xbf : Wobf;
        int i = ((isx ? bid : bid - 4096) * 256 + tid) * 8;
        float4 f0 = *(const float4*)&src[i];
        float4 f1 = *(const float4*)&src[i + 4];
        unsigned short t[8] __attribute__((aligned(16))) = {
            f2bf(f0.x), f2bf(f0.y), f2bf(f0.z), f2bf(f0.w),
            f2bf(f1.x), f2bf(f1.y), f2bf(f1.z), f2bf(f1.w)};
        *(u32x4*)&dst[i] = *(const u32x4*)t;
    } else {
        const int pid = bid - 4608;
        const int h = pid & 15, w3 = (pid >> 4) % 3, t = pid / 48;
        const float* src = (w3 == 0 ? Wq : (w3 == 1 ? Wk : Wv)) + h * D_ * DK_ + t * 64 * DK_;
        unsigned short* dst = Wt + (w3 * H_ + h) * DK_ * D_ + t * 64;
        const float wscale = (w3 == 0) ? 0.18033688011112042f : 1.0f;
        for (int rep = 0; rep < 16; ++rep) {
            int idx = rep * 256 + tid;
            int dl = idx >> 6, k = idx & 63;
            Ts[k * 65 + dl] = f2bf(src[dl * 64 + k] * wscale);
        }
        __syncthreads();
        for (int rep = 0; rep < 16; ++rep) {
            int idx = rep * 256 + tid;
            int kl = idx >> 6, dl = idx & 63;
            dst[kl * D_ + dl] = Ts[kl * 65 + dl];
        }
    }
}

// ---- async stage helpers: XOR-chunk swizzle (chunk ^= row&7), linear LDS dest ----
__device__ __forceinline__ void gload16(const unsigned short* gp, unsigned short* lp) {
    __builtin_amdgcn_global_load_lds((const __attribute__((address_space(1))) unsigned int*)gp,
                                     (__attribute__((address_space(3))) unsigned int*)lp,
                                     16, 0, 0);
}

// stage one 128-row half (h=0: rows 0-127, h=1: 128-255) of a 256x64 bf16 tile; 2 instr/wave
__device__ __forceinline__ void stage_half(const unsigned short* __restrict__ g,
                                           unsigned short* slot, int h, int wv, int lane, int ldg) {
#pragma unroll
    for (int L = 0; L < 2; ++L) {
        int rbase = h * 128 + L * 64 + wv * 8;
        int r = rbase + (lane >> 3);
        int gc = (lane & 7) ^ ((lane >> 3) & 7);
        gload16(g + r * ldg + gc * 8, slot + rbase * 64);
    }
}

// 64 rows x 64 cols, arbitrary row stride, 256 threads (attn); 2 loads/wave
__device__ __forceinline__ void stage64_async(const unsigned short* __restrict__ g,
                                              unsigned short* lds_base, int wv, int lane, int ldg) {
#pragma unroll
    for (int it = 0; it < 2; ++it) {
        int rbase = wv * 16 + it * 8;
        int r = rbase + (lane >> 3);
        int gc = (lane & 7) ^ ((lane >> 3) & 7);
        gload16(g + r * ldg + gc * 8, lds_base + rbase * 64);
    }
}

// ---- GEMM: C[256x256] = A[256x1024] * Bt[256x1024]^T  (m201 geometry) ----
// 8 waves (2M x 4N); per-wave output 128x64 as STRIDED fragments:
//   m-frag i (0..7): row = i*32 + wm*16 + (lane&15)   -> mh half = i>>2 aligns with A stage-halves
//   n-frag j (0..3): col = j*64 + wn*16 + (lane&15)   -> nh half = j>>1 aligns with B stage-halves
// 4 phases/K-tile, order (mh0,nA)(mh0,nB)(mh1,nB)(mh1,nA); af/bfA/bfB register-held so
// phase 3 does 0 LDS reads (24 ds_read_b128 / K-tile / wave vs 64 MFMA).
// Stage during tile j for j+1: p0 Ah0, p1 Bh0, p2 Bh1, p3 Ah1 (2 instr each; FIFO-derived
// counted waits vmcnt(6)/(6)/(6)/none; last tile (4)/(2)/(0); never drained mid-loop).
template <bool QKV_OUT>
__global__ __launch_bounds__(512, 2) void gemm256_kernel(const unsigned short* __restrict__ A,
                                                         const unsigned short* __restrict__ Bt,
                                                         void* __restrict__ Out,
                                                         unsigned short* __restrict__ VtOut) {
    __shared__ __align__(16) unsigned short lds[65536];  // 128 KB: A 2x16384, B 2x16384
    const int tid = threadIdx.x;
    const int wv = tid >> 6, lane = tid & 63, l15 = lane & 15, q4 = lane >> 4;
    const int wm = wv >> 2, wn = wv & 3;

    // bijective XCD-aware swizzle (nwg % 8 == 0: 384, 128)
    const int nwg = gridDim.x * gridDim.y;
    const int bid = blockIdx.x + blockIdx.y * gridDim.x;
    const int swz = (bid & 7) * (nwg >> 3) + (bid >> 3);
    const int bx = swz % gridDim.x, by = swz / gridDim.x;
    const int r0 = bx * 256, c0 = by * 256;

    const unsigned short* Ab = A + r0 * D_;
    const unsigned short* Bb = Bt + c0 * D_;

    f32x4 acc[8][4] = {};

    // prologue: tile 0 -> buf 0, FIFO order [Ah0, Bh0, Bh1, Ah1]
    stage_half(Ab, lds, 0, wv, lane, D_);
    stage_half(Bb, lds + 32768, 0, wv, lane, D_);
    stage_half(Bb, lds + 32768, 1, wv, lane, D_);
    stage_half(Ab, lds, 1, wv, lane, D_);

    for (int j = 0; j < 16; ++j) {
        const bool nx = (j + 1 < 16);
        unsigned short* Ad = lds + (j & 1) * 16384;
        unsigned short* Bd = lds + 32768 + (j & 1) * 16384;
        unsigned short* An = lds + ((j + 1) & 1) * 16384;
        unsigned short* Bn = lds + 32768 + ((j + 1) & 1) * 16384;

        bf16x8 af[4][2], bfA[2][2], bfB[2][2];

        // ---- phase 0: (mh0, nA); stage Ah0(j+1) ----
        if (nx) {
            stage_half(Ab + (j + 1) * 64, An, 0, wv, lane, D_);
            asm volatile("s_waitcnt vmcnt(6)" ::: "memory");
        } else {
            asm volatile("s_waitcnt vmcnt(4)" ::: "memory");
        }
        BAR();
#pragma unroll
        for (int kk = 0; kk < 2; ++kk) {
            const int sw = ((kk * 4 + q4) ^ (l15 & 7)) * 8;
#pragma unroll
            for (int i = 0; i < 4; ++i)
                af[i][kk] = *(const bf16x8*)&Ad[(i * 32 + wm * 16 + l15) * 64 + sw];
#pragma unroll
            for (int jf = 0; jf < 2; ++jf)
                bfA[jf][kk] = *(const bf16x8*)&Bd[(jf * 64 + wn * 16 + l15) * 64 + sw];
        }
        __builtin_amdgcn_s_setprio(1);
#pragma unroll
        for (int kk = 0; kk < 2; ++kk)
#pragma unroll
            for (int i = 0; i < 4; ++i)
#pragma unroll
                for (int jf = 0; jf < 2; ++jf)
                    acc[i][jf] = __builtin_amdgcn_mfma_f32_16x16x32_bf16(af[i][kk], bfA[jf][kk], acc[i][jf], 0, 0, 0);
        __builtin_amdgcn_s_setprio(0);

        // ---- phase 1: (mh0, nB); stage Bh0(j+1) ----
        if (nx) {
            stage_half(Bb + (j + 1) * 64, Bn, 0, wv, lane, D_);
            asm volatile("s_waitcnt vmcnt(6)" ::: "memory");
        } else {
            asm volatile("s_waitcnt vmcnt(2)" ::: "memory");
        }
        BAR();
#pragma unroll
        for (int kk = 0; kk < 2; ++kk) {
            const int sw = ((kk * 4 + q4) ^ (l15 & 7)) * 8;
#pragma unroll
            for (int jf = 0; jf < 2; ++jf)
                bfB[jf][kk] = *(const bf16x8*)&Bd[((2 + jf) * 64 + wn * 16 + l15) * 64 + sw];
        }
        __builtin_amdgcn_s_setprio(1);
#pragma unroll
        for (int kk = 0; kk < 2; ++kk)
#pragma unroll
            for (int i = 0; i < 4; ++i)
#pragma unroll
                for (int jf = 0; jf < 2; ++jf)
                    acc[i][2 + jf] = __builtin_amdgcn_mfma_f32_16x16x32_bf16(af[i][kk], bfB[jf][kk], acc[i][2 + jf], 0, 0, 0);
        __builtin_amdgcn_s_setprio(0);

        // ---- phase 2: (mh1, nB); stage Bh1(j+1) ----
        if (nx) {
            stage_half(Bb + (j + 1) * 64, Bn, 1, wv, lane, D_);
            asm volatile("s_waitcnt vmcnt(6)" ::: "memory");
        } else {
            asm volatile("s_waitcnt vmcnt(0)" ::: "memory");
        }
        BAR();
#pragma unroll
        for (int kk = 0; kk < 2; ++kk) {
            const int sw = ((kk * 4 + q4) ^ (l15 & 7)) * 8;
#pragma unroll
            for (int i = 0; i < 4; ++i)
                af[i][kk] = *(const bf16x8*)&Ad[(128 + i * 32 + wm * 16 + l15) * 64 + sw];
        }
        __builtin_amdgcn_s_setprio(1);
#pragma unroll
        for (int kk = 0; kk < 2; ++kk)
#pragma unroll
            for (int i = 0; i < 4; ++i)
#pragma unroll
                for (int jf = 0; jf < 2; ++jf)
                    acc[4 + i][2 + jf] = __builtin_amdgcn_mfma_f32_16x16x32_bf16(af[i][kk], bfB[jf][kk], acc[4 + i][2 + jf], 0, 0, 0);
        __builtin_amdgcn_s_setprio(0);

        // ---- phase 3: (mh1, nA); stage Ah1(j+1); zero LDS reads (af, bfA held) ----
        if (nx) stage_half(Ab + (j + 1) * 64, An, 1, wv, lane, D_);
        BAR();
        __builtin_amdgcn_s_setprio(1);
#pragma unroll
        for (int kk = 0; kk < 2; ++kk)
#pragma unroll
            for (int i = 0; i < 4; ++i)
#pragma unroll
                for (int jf = 0; jf < 2; ++jf)
                    acc[4 + i][jf] = __builtin_amdgcn_mfma_f32_16x16x32_bf16(af[i][kk], bfA[jf][kk], acc[4 + i][jf], 0, 0, 0);
        __builtin_amdgcn_s_setprio(0);
    }

    __syncthreads();  // drain + LDS reuse in epilogue

    if (QKV_OUT && c0 >= 2 * D_) {
        // V^T epilogue: full 256x256 tile transpose through the 128 KB LDS
        const int b = r0 >> 11, s0 = r0 & (S_ - 1);
#pragma unroll
        for (int mh = 0; mh < 2; ++mh)
#pragma unroll
            for (int ii = 0; ii < 4; ++ii)
#pragma unroll
                for (int jf = 0; jf < 4; ++jf)
#pragma unroll
                    for (int rr = 0; rr < 4; ++rr) {
                        int cl = jf * 64 + wn * 16 + l15;
                        int rl = mh * 128 + ii * 32 + wm * 16 + q4 * 4 + rr;
                        lds[cl * 256 + (rl ^ ((cl & 7) * 8))] = f2bf(acc[mh * 4 + ii][jf][rr]);
                    }
        __syncthreads();
#pragma unroll
        for (int rep = 0; rep < 16; ++rep) {
            int idx = rep * 512 + tid;
            int col = idx >> 5, ch = idx & 31;
            u32x4 v = *(const u32x4*)&lds[col * 256 + ((ch * 8) ^ ((col & 7) * 8))];
            int gcol = c0 + col;
            int vrow = b * 1024 + (gcol & 1023);
            *(u32x4*)&VtOut[vrow * S_ + s0 + ch * 8] = v;
        }
    } else {
#pragma unroll
        for (int mh = 0; mh < 2; ++mh)
#pragma unroll
            for (int ii = 0; ii < 4; ++ii)
#pragma unroll
                for (int jf = 0; jf < 4; ++jf)
#pragma unroll
                    for (int rr = 0; rr < 4; ++rr) {
                        int grow = r0 + mh * 128 + ii * 32 + wm * 16 + q4 * 4 + rr;
                        int gcol = c0 + jf * 64 + wn * 16 + l15;
                        if (QKV_OUT) {
                            int bb = grow >> 11, s = grow & (S_ - 1);
                            int w3 = gcol >> 10, h = (gcol >> 6) & 15, dk = gcol & 63;
                            ((unsigned short*)Out)[(((w3 * B_ + bb) * H_ + h) * S_ + s) * DK_ + dk] =
                                f2bf(acc[mh * 4 + ii][jf][rr]);
                        } else {
                            ((float*)Out)[grow * D_ + gcol] = acc[mh * 4 + ii][jf][rr];
                        }
                    }
    }
}

// ---- flash attention v8: depth-2 prefetch, mod-3 K/V buffers, raw barrier + counted
//      vmcnt (no per-tile vmcnt(0) drain). Per iter: wait vmcnt(4) [tile t done, t+1 in
//      flight] -> s_barrier -> issue stage(t+2) -> compute(t). One __syncthreads after
//      the Q register loads resets the compiler's vmcnt model so its auto-waits never
//      touch the counted staging queue. Compute identical to v7 (swapped QK^T +
//      in-register softmax transpose via cvt_pk + permlane swaps). ----
__global__ __launch_bounds__(256) void attn_kernel(const unsigned short* __restrict__ qkv,
                                                   unsigned short* __restrict__ concat) {
    static const int J[16] = {15, 13, 11, 9, 0, 2, 4, 6, 14, 12, 10, 8, 1, 3, 5, 7};
    const int bh = blockIdx.x;
    const int b = bh >> 4, h = bh & 15;
    const int j = J[blockIdx.y];
    const int q0 = j * 128;
    const int nk = 2 * j + 2;   // nk >= 2 always

    const unsigned short* Qp = qkv + ((0 * B_ + b) * H_ + h) * S_ * DK_;
    const unsigned short* Kp = qkv + ((1 * B_ + b) * H_ + h) * S_ * DK_;
    const unsigned short* Vt = qkv + 2 * B_ * H_ * S_ * DK_ + (b * H_ + h) * DK_ * S_;

    __shared__ __align__(16) unsigned short Kb[3][64 * 64];   // 24 KB
    __shared__ __align__(16) unsigned short Vb[3][64 * 64];   // 24 KB

    const int tid = threadIdx.x;
    const int wv = tid >> 6, lane = tid & 63, l15 = lane & 15, q4 = lane >> 4;

    // Q fragments FIRST (compiler-tracked register loads)...
    bf16x8 aq[2][2];
#pragma unroll
    for (int rt = 0; rt < 2; ++rt)
#pragma unroll
        for (int kk = 0; kk < 2; ++kk)
            aq[rt][kk] = *(const bf16x8*)&Qp[(q0 + wv * 32 + rt * 16 + l15) * DK_ + kk * 32 + q4 * 8];

    // ...then a full drain resets the compiler's vmcnt model: from here on, the ONLY
    // outstanding VMEM ops are our counted global_load_lds staging ops.
    __syncthreads();

    // prologue: stage tiles 0 and 1 (8 loads/wave outstanding)
    stage64_async(Kp, Kb[0], wv, lane, DK_);
    stage64_async(Vt, Vb[0], wv, lane, S_);
    stage64_async(Kp + 64 * DK_, Kb[1], wv, lane, DK_);
    stage64_async(Vt + 64, Vb[1], wv, lane, S_);

    f32x4 o[2][4] = {};
    float l_[2] = {0.0f, 0.0f};

    for (int t = 0; t < nk; ++t) {
        // wait for tile t's 4 loads (FIFO in-order retirement; t+1's 4 stay in flight)
        if (t + 1 < nk) asm volatile("s_waitcnt vmcnt(4)" ::: "memory");
        else            asm volatile("s_waitcnt vmcnt(0)" ::: "memory");
        BAR();  // all waves' tile-t loads done; buf (t+2)%3 readers (iter t-1) finished

        if (t + 2 < nk) {
            const int k2 = (t + 2) * 64;
            stage64_async(Kp + k2 * DK_, Kb[(t + 2) % 3], wv, lane, DK_);
            stage64_async(Vt + k2, Vb[(t + 2) % 3], wv, lane, S_);
        }
        const unsigned short* Kt = Kb[t % 3];
        const unsigned short* Vtt = Vb[t % 3];
        const int k0 = t * 64;

        // last k-tile (k0 = q0+64) is fully masked for waves 0,1 -> skip compute
        if ((t + 1 < nk) || (wv >= 2)) {
            // S^T = K Q^T : lane(l15,q4) holds S^T[k0+ct*16+q4*4+r][q0+wv*32+rt*16+l15]
            f32x4 sa[2][4] = {};
            __builtin_amdgcn_s_setprio(1);
#pragma unroll
            for (int kk = 0; kk < 2; ++kk) {
                const int sw = ((kk * 4 + q4) ^ (l15 & 7)) * 8;
#pragma unroll
                for (int ct = 0; ct < 4; ++ct) {
                    bf16x8 bk = *(const bf16x8*)&Kt[(ct * 16 + l15) * 64 + sw];
                    sa[0][ct] = __builtin_amdgcn_mfma_f32_16x16x32_bf16(bk, aq[0][kk], sa[0][ct], 0, 0, 0);
                    sa[1][ct] = __builtin_amdgcn_mfma_f32_16x16x32_bf16(bk, aq[1][kk], sa[1][ct], 0, 0, 0);
                }
            }
            __builtin_amdgcn_s_setprio(0);

            // p = exp2(s) — Wq carries (1/8)*log2(e); shift-free (softmax scale-invariant,
            // |s_scaled| <~ 15 so exp2 cannot overflow). Causal mask only on last two tiles.
            if (t < nk - 2) {
#pragma unroll
                for (int rt = 0; rt < 2; ++rt)
#pragma unroll
                    for (int ct = 0; ct < 4; ++ct)
#pragma unroll
                        for (int r = 0; r < 4; ++r)
                            sa[rt][ct][r] = __builtin_amdgcn_exp2f(sa[rt][ct][r]);
            } else {
                const int kb = k0 + q4 * 4;
#pragma unroll
                for (int rt = 0; rt < 2; ++rt) {
                    const int qrow = q0 + wv * 32 + rt * 16 + l15;
#pragma unroll
                    for (int ct = 0; ct < 4; ++ct)
#pragma unroll
                        for (int r = 0; r < 4; ++r) {
                            float e = __builtin_amdgcn_exp2f(sa[rt][ct][r]);
                            sa[rt][ct][r] = (kb + ct * 16 + r <= qrow) ? e : 0.0f;
                        }
                }
            }

            // row-sum (q = rt*16 + l15 lives entirely in-lane across ct,r)
#pragma unroll
            for (int rt = 0; rt < 2; ++rt)
#pragma unroll
                for (int ct = 0; ct < 4; ++ct)
                    l_[rt] += (sa[rt][ct][0] + sa[rt][ct][1]) + (sa[rt][ct][2] + sa[rt][ct][3]);

            // P^T -> PV A-fragments fully in-register (cvt_pk + permlane32/16 swaps)
            bf16x8 F[2][2];
#pragma unroll
            for (int rt = 0; rt < 2; ++rt)
#pragma unroll
                for (int kk = 0; kk < 2; ++kk) {
                    u32x4 w;
#pragma unroll
                    for (int u = 0; u < 2; ++u) {
                        unsigned int a = cvtpk_bf16(sa[rt][2 * kk][2 * u], sa[rt][2 * kk][2 * u + 1]);
                        unsigned int c = cvtpk_bf16(sa[rt][2 * kk + 1][2 * u], sa[rt][2 * kk + 1][2 * u + 1]);
                        asm("v_permlane32_swap_b32 %0, %1" : "+v"(a), "+v"(c));
                        asm("v_permlane16_swap_b32 %0, %1" : "+v"(a), "+v"(c));
                        w[u] = a;
                        w[2 + u] = c;
                    }
                    F[rt][kk] = *(const bf16x8*)&w;
                }

            // PV: A = F (registers), B = V^T fragments from LDS
            __builtin_amdgcn_s_setprio(1);
#pragma unroll
            for (int kk = 0; kk < 2; ++kk) {
                const int sw = ((kk * 4 + q4) ^ (l15 & 7)) * 8;
#pragma unroll
                for (int cd = 0; cd < 4; ++cd) {
                    bf16x8 bv = *(const bf16x8*)&Vtt[(cd * 16 + l15) * 64 + sw];
                    o[0][cd] = __builtin_amdgcn_mfma_f32_16x16x32_bf16(F[0][kk], bv, o[0][cd], 0, 0, 0);
                    o[1][cd] = __builtin_amdgcn_mfma_f32_16x16x32_bf16(F[1][kk], bv, o[1][cd], 0, 0, 0);
                }
            }
            __builtin_amdgcn_s_setprio(0);
        }
        // no trailing drain: next iteration's counted vmcnt + barrier covers everything
    }

    // epilogue: reduce l across the 4 lane-groups, redistribute to (q4,r) rows, normalize
#pragma unroll
    for (int rt = 0; rt < 2; ++rt) {
        float lr = l_[rt];
        lr += __shfl_xor(lr, 16);
        lr += __shfl_xor(lr, 32);
#pragma unroll
        for (int r = 0; r < 4; ++r) {
            float lfull = __shfl(lr, (lane & 48) | (q4 * 4 + r));
            float inv = 1.0f / fmaxf(lfull, 1.0e-37f);
            int row = q0 + wv * 32 + rt * 16 + q4 * 4 + r;
#pragma unroll
            for (int cd = 0; cd < 4; ++cd) {
                int col = h * DK_ + cd * 16 + l15;
                concat[(b * S_ + row) * D_ + col] = f2bf(o[rt][cd][r] * inv);
            }
        }
    }
}

extern "C" void kernel_launch(void* const* d_in, const int* in_sizes, int n_in,
                              void* d_out, int out_size, void* d_ws, size_t ws_size,
                              hipStream_t stream) {
    const float* x  = (const float*)d_in[0];
    const float* Wq = (const float*)d_in[1];
    const float* Wk = (const float*)d_in[2];
    const float* Wv = (const float*)d_in[3];
    const float* Wo = (const float*)d_in[4];

    unsigned short* qkv    = (unsigned short*)d_ws;          // 48 MB: Q,K [b][h][s][dk]; V^T [b][h][dk][s]
    unsigned short* Wt     = qkv + 3 * B_ * H_ * S_ * DK_;   //  6 MB
    unsigned short* xbf    = Wt + 3 * H_ * DK_ * D_;         // 16 MB — reused as concat after gemm<true>
    unsigned short* concat = xbf;
    unsigned short* VtOut  = qkv + 2 * B_ * H_ * S_ * DK_;

    const size_t need_shorts = (size_t)3 * B_ * H_ * S_ * DK_ + 3 * H_ * DK_ * D_ + B_ * S_ * D_ + D_ * D_;
    const bool sep = ws_size >= need_shorts * sizeof(unsigned short);

    if (sep) {
        unsigned short* Wobf = xbf + B_ * S_ * D_;
        prep_kernel<<<4096 + 512 + 768, 256, 0, stream>>>(x, Wq, Wk, Wv, Wo, xbf, Wt, Wobf);
        gemm256_kernel<true><<<dim3(32, 12), 512, 0, stream>>>(xbf, Wt, qkv, VtOut);
        attn_kernel<<<dim3(64, 16), 256, 0, stream>>>(qkv, concat);
        gemm256_kernel<false><<<dim3(32, 4), 512, 0, stream>>>(concat, Wobf, d_out, nullptr);
    } else {
        unsigned short* Wobf = Wt;  // sequential alias: Wt dead after gemm<true>
        cvt_kernel<<<B_ * S_ * D_ / 2048, 256, 0, stream>>>(x, xbf);
        prepack_kernel<<<dim3(H_, 3, 16), 256, 0, stream>>>(Wq, Wk, Wv, Wt);
        gemm256_kernel<true><<<dim3(32, 12), 512, 0, stream>>>(xbf, Wt, qkv, VtOut);
        cvt_kernel<<<D_ * D_ / 2048, 256, 0, stream>>>(Wo, Wobf);
        attn_kernel<<<dim3(64, 16), 256, 0, stream>>>(qkv, concat);
        gemm256_kernel<false><<<dim3(32, 4), 512, 0, stream>>>(concat, Wobf, d_out, nullptr);
    }
}

// Round 9
// 246.603 us; speedup vs baseline: 1.0170x; 1.0170x over previous
//
#include <hip/hip_runtime.h>
#include <hip/hip_bf16.h>

#define B_ 4
#define S_ 2048
#define D_ 1024
#define H_ 16
#define DK_ 64

typedef __attribute__((ext_vector_type(8))) short bf16x8;
typedef __attribute__((ext_vector_type(4))) float f32x4;
typedef __attribute__((ext_vector_type(4))) unsigned int u32x4;

__device__ __forceinline__ unsigned short f2bf(float f) {
    unsigned int u = __float_as_uint(f);
    u += 0x7FFFu + ((u >> 16) & 1u);
    return (unsigned short)(u >> 16);
}

__device__ __forceinline__ unsigned int cvtpk_bf16(float lo, float hi) {
    unsigned int r;
    asm("v_cvt_pk_bf16_f32 %0, %1, %2" : "=v"(r) : "v"(lo), "v"(hi));
    return r;
}

#define BAR() do { __builtin_amdgcn_s_barrier(); asm volatile("" ::: "memory"); } while (0)

// ---- fp32 -> bf16 bulk convert (n multiple of 2048) ----
__global__ void cvt_kernel(const float* __restrict__ src, unsigned short* __restrict__ dst) {
    int i = (blockIdx.x * 256 + threadIdx.x) * 8;
    float4 f0 = *(const float4*)&src[i];
    float4 f1 = *(const float4*)&src[i + 4];
    unsigned short t[8] __attribute__((aligned(16))) = {
        f2bf(f0.x), f2bf(f0.y), f2bf(f0.z), f2bf(f0.w),
        f2bf(f1.x), f2bf(f1.y), f2bf(f1.z), f2bf(f1.w)};
    *(u32x4*)&dst[i] = *(const u32x4*)t;
}

// ---- prepack: Wq/Wk/Wv fp32 [H][D][DK] -> bf16 Wt [3*H*DK][D] via LDS transpose ----
// Wq is pre-scaled by log2(e)/8 so attention scores come out of QK^T ready for exp2.
__global__ void prepack_kernel(const float* __restrict__ Wq,
                               const float* __restrict__ Wk,
                               const float* __restrict__ Wv,
                               unsigned short* __restrict__ Wt) {
    __shared__ unsigned short Ts[64 * 65];
    int h = blockIdx.x, w3 = blockIdx.y, t = blockIdx.z;
    const float* src = (w3 == 0 ? Wq : (w3 == 1 ? Wk : Wv)) + h * D_ * DK_ + t * 64 * DK_;
    unsigned short* dst = Wt + (w3 * H_ + h) * DK_ * D_ + t * 64;
    const float wscale = (w3 == 0) ? 0.18033688011112042f : 1.0f;  // (1/sqrt(64)) * log2(e)
    int tid = threadIdx.x;
    for (int rep = 0; rep < 16; ++rep) {
        int idx = rep * 256 + tid;
        int dl = idx >> 6, k = idx & 63;
        Ts[k * 65 + dl] = f2bf(src[dl * 64 + k] * wscale);
    }
    __syncthreads();
    for (int rep = 0; rep < 16; ++rep) {
        int idx = rep * 256 + tid;
        int kl = idx >> 6, dl = idx & 63;
        dst[kl * D_ + dl] = Ts[kl * 65 + dl];
    }
}

// ---- merged prep: cvt(x) [4096 blocks] + cvt(Wo) [512 blocks] + prepack [768 blocks] ----
__global__ __launch_bounds__(256) void prep_kernel(const float* __restrict__ x,
                                                   const float* __restrict__ Wq,
                                                   const float* __restrict__ Wk,
                                                   const float* __restrict__ Wv,
                                                   const float* __restrict__ Wo,
                                                   unsigned short* __restrict__ xbf,
                                                   unsigned short* __restrict__ Wt,
                                                   unsigned short* __restrict__ Wobf) {
    __shared__ unsigned short Ts[64 * 65];
    const int bid = blockIdx.x;
    const int tid = threadIdx.x;
    if (bid < 4096 + 512) {
        const bool isx = bid < 4096;
        const float* src = isx ? x : Wo;
        unsigned short* dst = isx ? xbf : Wobf;
        int i = ((isx ? bid : bid - 4096) * 256 + tid) * 8;
        float4 f0 = *(const float4*)&src[i];
        float4 f1 = *(const float4*)&src[i + 4];
        unsigned short t[8] __attribute__((aligned(16))) = {
            f2bf(f0.x), f2bf(f0.y), f2bf(f0.z), f2bf(f0.w),
            f2bf(f1.x), f2bf(f1.y), f2bf(f1.z), f2bf(f1.w)};
        *(u32x4*)&dst[i] = *(const u32x4*)t;
    } else {
        const int pid = bid - 4608;
        const int h = pid & 15, w3 = (pid >> 4) % 3, t = pid / 48;
        const float* src = (w3 == 0 ? Wq : (w3 == 1 ? Wk : Wv)) + h * D_ * DK_ + t * 64 * DK_;
        unsigned short* dst = Wt + (w3 * H_ + h) * DK_ * D_ + t * 64;
        const float wscale = (w3 == 0) ? 0.18033688011112042f : 1.0f;
        for (int rep = 0; rep < 16; ++rep) {
            int idx = rep * 256 + tid;
            int dl = idx >> 6, k = idx & 63;
            Ts[k * 65 + dl] = f2bf(src[dl * 64 + k] * wscale);
        }
        __syncthreads();
        for (int rep = 0; rep < 16; ++rep) {
            int idx = rep * 256 + tid;
            int kl = idx >> 6, dl = idx & 63;
            dst[kl * D_ + dl] = Ts[kl * 65 + dl];
        }
    }
}

// ---- async stage helpers: XOR-chunk swizzle (chunk ^= row&7), linear LDS dest ----
__device__ __forceinline__ void gload16(const unsigned short* gp, unsigned short* lp) {
    __builtin_amdgcn_global_load_lds((const __attribute__((address_space(1))) unsigned int*)gp,
                                     (__attribute__((address_space(3))) unsigned int*)lp,
                                     16, 0, 0);
}

// stage one 128-row half (h=0: rows 0-127, h=1: 128-255) of a 256x64 bf16 tile; 2 instr/wave (512 thr)
__device__ __forceinline__ void stage_half(const unsigned short* __restrict__ g,
                                           unsigned short* slot, int h, int wv, int lane, int ldg) {
#pragma unroll
    for (int L = 0; L < 2; ++L) {
        int rbase = h * 128 + L * 64 + wv * 8;
        int r = rbase + (lane >> 3);
        int gc = (lane & 7) ^ ((lane >> 3) & 7);
        gload16(g + r * ldg + gc * 8, slot + rbase * 64);
    }
}

// 64 rows x 64 cols bf16 (8 KB): 1 load/thread at 512 threads
__device__ __forceinline__ void stageA_half(const unsigned short* __restrict__ g,
                                            unsigned short* lds_base, int wv, int lane, int ldg) {
    int r = wv * 8 + (lane >> 3);
    int gc = (lane & 7) ^ ((lane >> 3) & 7);
    gload16(g + r * ldg + gc * 8, lds_base + (wv * 8) * 64);
}

// 128 rows x 64 cols bf16 (16 KB): 2 loads/thread at 512 threads
__device__ __forceinline__ void stageB_half(const unsigned short* __restrict__ g,
                                            unsigned short* lds_base, int wv, int lane, int ldg) {
#pragma unroll
    for (int L = 0; L < 2; ++L) {
        int rbase = wv * 16 + L * 8;
        int r = rbase + (lane >> 3);
        int gc = (lane & 7) ^ ((lane >> 3) & 7);
        gload16(g + r * ldg + gc * 8, lds_base + rbase * 64);
    }
}

// 64 rows x 64 cols, arbitrary row stride, 256 threads (attn); 2 loads/wave
__device__ __forceinline__ void stage64_async(const unsigned short* __restrict__ g,
                                              unsigned short* lds_base, int wv, int lane, int ldg) {
#pragma unroll
    for (int it = 0; it < 2; ++it) {
        int rbase = wv * 16 + it * 8;
        int r = rbase + (lane >> 3);
        int gc = (lane & 7) ^ ((lane >> 3) & 7);
        gload16(g + r * ldg + gc * 8, lds_base + rbase * 64);
    }
}

// ---- GEMM A: C[256x256] = A[256x1024]*Bt[256x1024]^T (m201 geometry) — used for QKV ----
// 8 waves; per-wave 128x64 strided frags; 4 phases/K-tile; counted vmcnt(6); see r6 notes.
template <bool QKV_OUT>
__global__ __launch_bounds__(512, 2) void gemm256_kernel(const unsigned short* __restrict__ A,
                                                         const unsigned short* __restrict__ Bt,
                                                         void* __restrict__ Out,
                                                         unsigned short* __restrict__ VtOut) {
    __shared__ __align__(16) unsigned short lds[65536];  // 128 KB: A 2x16384, B 2x16384
    const int tid = threadIdx.x;
    const int wv = tid >> 6, lane = tid & 63, l15 = lane & 15, q4 = lane >> 4;
    const int wm = wv >> 2, wn = wv & 3;

    const int nwg = gridDim.x * gridDim.y;
    const int bid = blockIdx.x + blockIdx.y * gridDim.x;
    const int swz = (bid & 7) * (nwg >> 3) + (bid >> 3);
    const int bx = swz % gridDim.x, by = swz / gridDim.x;
    const int r0 = bx * 256, c0 = by * 256;

    const unsigned short* Ab = A + r0 * D_;
    const unsigned short* Bb = Bt + c0 * D_;

    f32x4 acc[8][4] = {};

    stage_half(Ab, lds, 0, wv, lane, D_);
    stage_half(Bb, lds + 32768, 0, wv, lane, D_);
    stage_half(Bb, lds + 32768, 1, wv, lane, D_);
    stage_half(Ab, lds, 1, wv, lane, D_);

    for (int j = 0; j < 16; ++j) {
        const bool nx = (j + 1 < 16);
        unsigned short* Ad = lds + (j & 1) * 16384;
        unsigned short* Bd = lds + 32768 + (j & 1) * 16384;
        unsigned short* An = lds + ((j + 1) & 1) * 16384;
        unsigned short* Bn = lds + 32768 + ((j + 1) & 1) * 16384;

        bf16x8 af[4][2], bfA[2][2], bfB[2][2];

        // phase 0: (mh0, nA); stage Ah0(j+1)
        if (nx) {
            stage_half(Ab + (j + 1) * 64, An, 0, wv, lane, D_);
            asm volatile("s_waitcnt vmcnt(6)" ::: "memory");
        } else {
            asm volatile("s_waitcnt vmcnt(4)" ::: "memory");
        }
        BAR();
#pragma unroll
        for (int kk = 0; kk < 2; ++kk) {
            const int sw = ((kk * 4 + q4) ^ (l15 & 7)) * 8;
#pragma unroll
            for (int i = 0; i < 4; ++i)
                af[i][kk] = *(const bf16x8*)&Ad[(i * 32 + wm * 16 + l15) * 64 + sw];
#pragma unroll
            for (int jf = 0; jf < 2; ++jf)
                bfA[jf][kk] = *(const bf16x8*)&Bd[(jf * 64 + wn * 16 + l15) * 64 + sw];
        }
        __builtin_amdgcn_s_setprio(1);
#pragma unroll
        for (int kk = 0; kk < 2; ++kk)
#pragma unroll
            for (int i = 0; i < 4; ++i)
#pragma unroll
                for (int jf = 0; jf < 2; ++jf)
                    acc[i][jf] = __builtin_amdgcn_mfma_f32_16x16x32_bf16(af[i][kk], bfA[jf][kk], acc[i][jf], 0, 0, 0);
        __builtin_amdgcn_s_setprio(0);

        // phase 1: (mh0, nB); stage Bh0(j+1)
        if (nx) {
            stage_half(Bb + (j + 1) * 64, Bn, 0, wv, lane, D_);
            asm volatile("s_waitcnt vmcnt(6)" ::: "memory");
        } else {
            asm volatile("s_waitcnt vmcnt(2)" ::: "memory");
        }
        BAR();
#pragma unroll
        for (int kk = 0; kk < 2; ++kk) {
            const int sw = ((kk * 4 + q4) ^ (l15 & 7)) * 8;
#pragma unroll
            for (int jf = 0; jf < 2; ++jf)
                bfB[jf][kk] = *(const bf16x8*)&Bd[((2 + jf) * 64 + wn * 16 + l15) * 64 + sw];
        }
        __builtin_amdgcn_s_setprio(1);
#pragma unroll
        for (int kk = 0; kk < 2; ++kk)
#pragma unroll
            for (int i = 0; i < 4; ++i)
#pragma unroll
                for (int jf = 0; jf < 2; ++jf)
                    acc[i][2 + jf] = __builtin_amdgcn_mfma_f32_16x16x32_bf16(af[i][kk], bfB[jf][kk], acc[i][2 + jf], 0, 0, 0);
        __builtin_amdgcn_s_setprio(0);

        // phase 2: (mh1, nB); stage Bh1(j+1)
        if (nx) {
            stage_half(Bb + (j + 1) * 64, Bn, 1, wv, lane, D_);
            asm volatile("s_waitcnt vmcnt(6)" ::: "memory");
        } else {
            asm volatile("s_waitcnt vmcnt(0)" ::: "memory");
        }
        BAR();
#pragma unroll
        for (int kk = 0; kk < 2; ++kk) {
            const int sw = ((kk * 4 + q4) ^ (l15 & 7)) * 8;
#pragma unroll
            for (int i = 0; i < 4; ++i)
                af[i][kk] = *(const bf16x8*)&Ad[(128 + i * 32 + wm * 16 + l15) * 64 + sw];
        }
        __builtin_amdgcn_s_setprio(1);
#pragma unroll
        for (int kk = 0; kk < 2; ++kk)
#pragma unroll
            for (int i = 0; i < 4; ++i)
#pragma unroll
                for (int jf = 0; jf < 2; ++jf)
                    acc[4 + i][2 + jf] = __builtin_amdgcn_mfma_f32_16x16x32_bf16(af[i][kk], bfB[jf][kk], acc[4 + i][2 + jf], 0, 0, 0);
        __builtin_amdgcn_s_setprio(0);

        // phase 3: (mh1, nA); stage Ah1(j+1); zero LDS reads
        if (nx) stage_half(Ab + (j + 1) * 64, An, 1, wv, lane, D_);
        BAR();
        __builtin_amdgcn_s_setprio(1);
#pragma unroll
        for (int kk = 0; kk < 2; ++kk)
#pragma unroll
            for (int i = 0; i < 4; ++i)
#pragma unroll
                for (int jf = 0; jf < 2; ++jf)
                    acc[4 + i][jf] = __builtin_amdgcn_mfma_f32_16x16x32_bf16(af[i][kk], bfA[jf][kk], acc[4 + i][jf], 0, 0, 0);
        __builtin_amdgcn_s_setprio(0);
    }

    __syncthreads();

    if (QKV_OUT && c0 >= 2 * D_) {
        const int b = r0 >> 11, s0 = r0 & (S_ - 1);
#pragma unroll
        for (int mh = 0; mh < 2; ++mh)
#pragma unroll
            for (int ii = 0; ii < 4; ++ii)
#pragma unroll
                for (int jf = 0; jf < 4; ++jf)
#pragma unroll
                    for (int rr = 0; rr < 4; ++rr) {
                        int cl = jf * 64 + wn * 16 + l15;
                        int rl = mh * 128 + ii * 32 + wm * 16 + q4 * 4 + rr;
                        lds[cl * 256 + (rl ^ ((cl & 7) * 8))] = f2bf(acc[mh * 4 + ii][jf][rr]);
                    }
        __syncthreads();
#pragma unroll
        for (int rep = 0; rep < 16; ++rep) {
            int idx = rep * 512 + tid;
            int col = idx >> 5, ch = idx & 31;
            u32x4 v = *(const u32x4*)&lds[col * 256 + ((ch * 8) ^ ((col & 7) * 8))];
            int gcol = c0 + col;
            int vrow = b * 1024 + (gcol & 1023);
            *(u32x4*)&VtOut[vrow * S_ + s0 + ch * 8] = v;
        }
    } else {
#pragma unroll
        for (int mh = 0; mh < 2; ++mh)
#pragma unroll
            for (int ii = 0; ii < 4; ++ii)
#pragma unroll
                for (int jf = 0; jf < 4; ++jf)
#pragma unroll
                    for (int rr = 0; rr < 4; ++rr) {
                        int grow = r0 + mh * 128 + ii * 32 + wm * 16 + q4 * 4 + rr;
                        int gcol = c0 + jf * 64 + wn * 16 + l15;
                        if (QKV_OUT) {
                            int bb = grow >> 11, s = grow & (S_ - 1);
                            int w3 = gcol >> 10, h = (gcol >> 6) & 15, dk = gcol & 63;
                            ((unsigned short*)Out)[(((w3 * B_ + bb) * H_ + h) * S_ + s) * DK_ + dk] =
                                f2bf(acc[mh * 4 + ii][jf][rr]);
                        } else {
                            ((float*)Out)[grow * D_ + gcol] = acc[mh * 4 + ii][jf][rr];
                        }
                    }
    }
}

// ---- phase MFMA cluster for GEMM B (quadrant (MH,NH), 8 ds_read + 8 MFMA) ----
template <int MH, int NH>
__device__ __forceinline__ void phase_mfma(const unsigned short* Asl, const unsigned short* Bsl,
                                           int db, int wm, int wn, int l15, int q4,
                                           f32x4 (&acc)[2][2][2][2]) {
    bf16x8 af[2][2], bf[2][2];
#pragma unroll
    for (int kk = 0; kk < 2; ++kk) {
        const int sw = ((kk * 4 + q4) ^ (l15 & 7)) * 8;
#pragma unroll
        for (int m4 = 0; m4 < 2; ++m4)
            af[m4][kk] = *(const bf16x8*)&Asl[(db + MH) * 4096 + (wm * 32 + m4 * 16 + l15) * 64 + sw];
#pragma unroll
        for (int n2 = 0; n2 < 2; ++n2)
            bf[n2][kk] = *(const bf16x8*)&Bsl[(db + NH) * 8192 + (wn * 32 + n2 * 16 + l15) * 64 + sw];
    }
    __builtin_amdgcn_s_setprio(1);
#pragma unroll
    for (int kk = 0; kk < 2; ++kk)
#pragma unroll
        for (int m4 = 0; m4 < 2; ++m4)
#pragma unroll
            for (int n2 = 0; n2 < 2; ++n2)
                acc[MH][NH][m4][n2] =
                    __builtin_amdgcn_mfma_f32_16x16x32_bf16(af[m4][kk], bf[n2][kk], acc[MH][NH][m4][n2], 0, 0, 0);
    __builtin_amdgcn_s_setprio(0);
}

// ---- GEMM B: C[128x256] = A[128x1024]*Bt[256x1024]^T (round-4/5 kernel, verified) ----
// Used for the output projection: grid (64,4) = 256 blocks = 1 balanced round, all CUs.
__global__ __launch_bounds__(512) void gemm128_kernel(const unsigned short* __restrict__ A,
                                                      const unsigned short* __restrict__ Bt,
                                                      float* __restrict__ Out) {
    __shared__ __align__(16) unsigned short lds[49152];  // 96 KB: A 4x4096, B 4x8192
    unsigned short* Asl = lds;
    unsigned short* Bsl = lds + 16384;

    const int tid = threadIdx.x;
    const int wv = tid >> 6, lane = tid & 63, l15 = lane & 15, q4 = lane >> 4;
    const int wm = wv >> 2, wn = wv & 3;

    const int nwg = gridDim.x * gridDim.y;
    const int bid = blockIdx.x + blockIdx.y * gridDim.x;
    const int swz = (bid & 7) * (nwg >> 3) + (bid >> 3);
    const int bx = swz % gridDim.x, by = swz / gridDim.x;
    const int r0 = bx * 128, c0 = by * 256;

    const unsigned short* Ab = A + r0 * D_;
    const unsigned short* Bb = Bt + c0 * D_;

    f32x4 acc[2][2][2][2] = {};

    stageA_half(Ab, Asl, wv, lane, D_);
    stageB_half(Bb, Bsl, wv, lane, D_);
    stageB_half(Bb + 128 * D_, Bsl + 8192, wv, lane, D_);

    for (int j = 0; j < 16; ++j) {
        const int db = (j & 1) * 2;
        const int ndb = ((j + 1) & 1) * 2;
        const bool nx = (j + 1 < 16);

        stageA_half(Ab + 64 * D_ + j * 64, Asl + (db + 1) * 4096, wv, lane, D_);
        asm volatile("s_waitcnt vmcnt(3)" ::: "memory");
        BAR();
        phase_mfma<0, 0>(Asl, Bsl, db, wm, wn, l15, q4, acc);

        if (nx) {
            stageA_half(Ab + (j + 1) * 64, Asl + (ndb + 0) * 4096, wv, lane, D_);
            asm volatile("s_waitcnt vmcnt(2)" ::: "memory");
        } else {
            asm volatile("s_waitcnt vmcnt(1)" ::: "memory");
        }
        BAR();
        phase_mfma<0, 1>(Asl, Bsl, db, wm, wn, l15, q4, acc);

        if (nx) {
            stageB_half(Bb + (j + 1) * 64, Bsl + (ndb + 0) * 8192, wv, lane, D_);
            asm volatile("s_waitcnt vmcnt(3)" ::: "memory");
        } else {
            asm volatile("s_waitcnt vmcnt(0)" ::: "memory");
        }
        BAR();
        phase_mfma<1, 1>(Asl, Bsl, db, wm, wn, l15, q4, acc);

        if (nx) stageB_half(Bb + 128 * D_ + (j + 1) * 64, Bsl + (ndb + 1) * 8192, wv, lane, D_);
        BAR();
        phase_mfma<1, 0>(Asl, Bsl, db, wm, wn, l15, q4, acc);
    }

    __syncthreads();

#pragma unroll
    for (int mh = 0; mh < 2; ++mh)
#pragma unroll
        for (int nh = 0; nh < 2; ++nh)
#pragma unroll
            for (int m4 = 0; m4 < 2; ++m4)
#pragma unroll
                for (int n2 = 0; n2 < 2; ++n2)
#pragma unroll
                    for (int rr = 0; rr < 4; ++rr) {
                        int grow = r0 + mh * 64 + wm * 32 + m4 * 16 + q4 * 4 + rr;
                        int gcol = c0 + nh * 128 + wn * 32 + n2 * 16 + l15;
                        Out[grow * D_ + gcol] = acc[mh][nh][m4][n2][rr];
                    }
}

// ---- flash attention v8 (unchanged from r7): depth-2 prefetch, mod-3 K/V buffers,
//      raw barrier + counted vmcnt; swapped QK^T + in-register softmax transpose ----
__global__ __launch_bounds__(256) void attn_kernel(const unsigned short* __restrict__ qkv,
                                                   unsigned short* __restrict__ concat) {
    static const int J[16] = {15, 13, 11, 9, 0, 2, 4, 6, 14, 12, 10, 8, 1, 3, 5, 7};
    const int bh = blockIdx.x;
    const int b = bh >> 4, h = bh & 15;
    const int j = J[blockIdx.y];
    const int q0 = j * 128;
    const int nk = 2 * j + 2;

    const unsigned short* Qp = qkv + ((0 * B_ + b) * H_ + h) * S_ * DK_;
    const unsigned short* Kp = qkv + ((1 * B_ + b) * H_ + h) * S_ * DK_;
    const unsigned short* Vt = qkv + 2 * B_ * H_ * S_ * DK_ + (b * H_ + h) * DK_ * S_;

    __shared__ __align__(16) unsigned short Kb[3][64 * 64];
    __shared__ __align__(16) unsigned short Vb[3][64 * 64];

    const int tid = threadIdx.x;
    const int wv = tid >> 6, lane = tid & 63, l15 = lane & 15, q4 = lane >> 4;

    bf16x8 aq[2][2];
#pragma unroll
    for (int rt = 0; rt < 2; ++rt)
#pragma unroll
        for (int kk = 0; kk < 2; ++kk)
            aq[rt][kk] = *(const bf16x8*)&Qp[(q0 + wv * 32 + rt * 16 + l15) * DK_ + kk * 32 + q4 * 8];

    __syncthreads();  // reset compiler vmcnt model before counted staging

    stage64_async(Kp, Kb[0], wv, lane, DK_);
    stage64_async(Vt, Vb[0], wv, lane, S_);
    stage64_async(Kp + 64 * DK_, Kb[1], wv, lane, DK_);
    stage64_async(Vt + 64, Vb[1], wv, lane, S_);

    f32x4 o[2][4] = {};
    float l_[2] = {0.0f, 0.0f};

    for (int t = 0; t < nk; ++t) {
        if (t + 1 < nk) asm volatile("s_waitcnt vmcnt(4)" ::: "memory");
        else            asm volatile("s_waitcnt vmcnt(0)" ::: "memory");
        BAR();

        if (t + 2 < nk) {
            const int k2 = (t + 2) * 64;
            stage64_async(Kp + k2 * DK_, Kb[(t + 2) % 3], wv, lane, DK_);
            stage64_async(Vt + k2, Vb[(t + 2) % 3], wv, lane, S_);
        }
        const unsigned short* Kt = Kb[t % 3];
        const unsigned short* Vtt = Vb[t % 3];
        const int k0 = t * 64;

        if ((t + 1 < nk) || (wv >= 2)) {
            f32x4 sa[2][4] = {};
            __builtin_amdgcn_s_setprio(1);
#pragma unroll
            for (int kk = 0; kk < 2; ++kk) {
                const int sw = ((kk * 4 + q4) ^ (l15 & 7)) * 8;
#pragma unroll
                for (int ct = 0; ct < 4; ++ct) {
                    bf16x8 bk = *(const bf16x8*)&Kt[(ct * 16 + l15) * 64 + sw];
                    sa[0][ct] = __builtin_amdgcn_mfma_f32_16x16x32_bf16(bk, aq[0][kk], sa[0][ct], 0, 0, 0);
                    sa[1][ct] = __builtin_amdgcn_mfma_f32_16x16x32_bf16(bk, aq[1][kk], sa[1][ct], 0, 0, 0);
                }
            }
            __builtin_amdgcn_s_setprio(0);

            if (t < nk - 2) {
#pragma unroll
                for (int rt = 0; rt < 2; ++rt)
#pragma unroll
                    for (int ct = 0; ct < 4; ++ct)
#pragma unroll
                        for (int r = 0; r < 4; ++r)
                            sa[rt][ct][r] = __builtin_amdgcn_exp2f(sa[rt][ct][r]);
            } else {
                const int kb = k0 + q4 * 4;
#pragma unroll
                for (int rt = 0; rt < 2; ++rt) {
                    const int qrow = q0 + wv * 32 + rt * 16 + l15;
#pragma unroll
                    for (int ct = 0; ct < 4; ++ct)
#pragma unroll
                        for (int r = 0; r < 4; ++r) {
                            float e = __builtin_amdgcn_exp2f(sa[rt][ct][r]);
                            sa[rt][ct][r] = (kb + ct * 16 + r <= qrow) ? e : 0.0f;
                        }
                }
            }

#pragma unroll
            for (int rt = 0; rt < 2; ++rt)
#pragma unroll
                for (int ct = 0; ct < 4; ++ct)
                    l_[rt] += (sa[rt][ct][0] + sa[rt][ct][1]) + (sa[rt][ct][2] + sa[rt][ct][3]);

            bf16x8 F[2][2];
#pragma unroll
            for (int rt = 0; rt < 2; ++rt)
#pragma unroll
                for (int kk = 0; kk < 2; ++kk) {
                    u32x4 w;
#pragma unroll
                    for (int u = 0; u < 2; ++u) {
                        unsigned int a = cvtpk_bf16(sa[rt][2 * kk][2 * u], sa[rt][2 * kk][2 * u + 1]);
                        unsigned int c = cvtpk_bf16(sa[rt][2 * kk + 1][2 * u], sa[rt][2 * kk + 1][2 * u + 1]);
                        asm("v_permlane32_swap_b32 %0, %1" : "+v"(a), "+v"(c));
                        asm("v_permlane16_swap_b32 %0, %1" : "+v"(a), "+v"(c));
                        w[u] = a;
                        w[2 + u] = c;
                    }
                    F[rt][kk] = *(const bf16x8*)&w;
                }

            __builtin_amdgcn_s_setprio(1);
#pragma unroll
            for (int kk = 0; kk < 2; ++kk) {
                const int sw = ((kk * 4 + q4) ^ (l15 & 7)) * 8;
#pragma unroll
                for (int cd = 0; cd < 4; ++cd) {
                    bf16x8 bv = *(const bf16x8*)&Vtt[(cd * 16 + l15) * 64 + sw];
                    o[0][cd] = __builtin_amdgcn_mfma_f32_16x16x32_bf16(F[0][kk], bv, o[0][cd], 0, 0, 0);
                    o[1][cd] = __builtin_amdgcn_mfma_f32_16x16x32_bf16(F[1][kk], bv, o[1][cd], 0, 0, 0);
                }
            }
            __builtin_amdgcn_s_setprio(0);
        }
    }

#pragma unroll
    for (int rt = 0; rt < 2; ++rt) {
        float lr = l_[rt];
        lr += __shfl_xor(lr, 16);
        lr += __shfl_xor(lr, 32);
#pragma unroll
        for (int r = 0; r < 4; ++r) {
            float lfull = __shfl(lr, (lane & 48) | (q4 * 4 + r));
            float inv = 1.0f / fmaxf(lfull, 1.0e-37f);
            int row = q0 + wv * 32 + rt * 16 + q4 * 4 + r;
#pragma unroll
            for (int cd = 0; cd < 4; ++cd) {
                int col = h * DK_ + cd * 16 + l15;
                concat[(b * S_ + row) * D_ + col] = f2bf(o[rt][cd][r] * inv);
            }
        }
    }
}

extern "C" void kernel_launch(void* const* d_in, const int* in_sizes, int n_in,
                              void* d_out, int out_size, void* d_ws, size_t ws_size,
                              hipStream_t stream) {
    const float* x  = (const float*)d_in[0];
    const float* Wq = (const float*)d_in[1];
    const float* Wk = (const float*)d_in[2];
    const float* Wv = (const float*)d_in[3];
    const float* Wo = (const float*)d_in[4];

    unsigned short* qkv    = (unsigned short*)d_ws;          // 48 MB: Q,K [b][h][s][dk]; V^T [b][h][dk][s]
    unsigned short* Wt     = qkv + 3 * B_ * H_ * S_ * DK_;   //  6 MB
    unsigned short* xbf    = Wt + 3 * H_ * DK_ * D_;         // 16 MB — reused as concat after gemm<true>
    unsigned short* concat = xbf;
    unsigned short* VtOut  = qkv + 2 * B_ * H_ * S_ * DK_;

    const size_t need_shorts = (size_t)3 * B_ * H_ * S_ * DK_ + 3 * H_ * DK_ * D_ + B_ * S_ * D_ + D_ * D_;
    const bool sep = ws_size >= need_shorts * sizeof(unsigned short);

    if (sep) {
        unsigned short* Wobf = xbf + B_ * S_ * D_;
        prep_kernel<<<4096 + 512 + 768, 256, 0, stream>>>(x, Wq, Wk, Wv, Wo, xbf, Wt, Wobf);
        gemm256_kernel<true><<<dim3(32, 12), 512, 0, stream>>>(xbf, Wt, qkv, VtOut);
        attn_kernel<<<dim3(64, 16), 256, 0, stream>>>(qkv, concat);
        gemm128_kernel<<<dim3(64, 4), 512, 0, stream>>>(concat, Wobf, (float*)d_out);
    } else {
        unsigned short* Wobf = Wt;  // sequential alias: Wt dead after gemm<true>
        cvt_kernel<<<B_ * S_ * D_ / 2048, 256, 0, stream>>>(x, xbf);
        prepack_kernel<<<dim3(H_, 3, 16), 256, 0, stream>>>(Wq, Wk, Wv, Wt);
        gemm256_kernel<true><<<dim3(32, 12), 512, 0, stream>>>(xbf, Wt, qkv, VtOut);
        cvt_kernel<<<D_ * D_ / 2048, 256, 0, stream>>>(Wo, Wobf);
        attn_kernel<<<dim3(64, 16), 256, 0, stream>>>(qkv, concat);
        gemm128_kernel<<<dim3(64, 4), 512, 0, stream>>>(concat, Wobf, (float*)d_out);
    }
}

// Round 10
// 244.254 us; speedup vs baseline: 1.0267x; 1.0096x over previous
//
#include <hip/hip_runtime.h>
#include <hip/hip_bf16.h>

#define B_ 4
#define S_ 2048
#define D_ 1024
#define H_ 16
#define DK_ 64

typedef __attribute__((ext_vector_type(8))) short bf16x8;
typedef __attribute__((ext_vector_type(4))) float f32x4;
typedef __attribute__((ext_vector_type(4))) unsigned int u32x4;

__device__ __forceinline__ unsigned short f2bf(float f) {
    unsigned int u = __float_as_uint(f);
    u += 0x7FFFu + ((u >> 16) & 1u);
    return (unsigned short)(u >> 16);
}

__device__ __forceinline__ unsigned int cvtpk_bf16(float lo, float hi) {
    unsigned int r;
    asm("v_cvt_pk_bf16_f32 %0, %1, %2" : "=v"(r) : "v"(lo), "v"(hi));
    return r;
}

#define BAR() do { __builtin_amdgcn_s_barrier(); asm volatile("" ::: "memory"); } while (0)

// ---- fp32 -> bf16 bulk convert (n multiple of 2048) ----
__global__ void cvt_kernel(const float* __restrict__ src, unsigned short* __restrict__ dst) {
    int i = (blockIdx.x * 256 + threadIdx.x) * 8;
    float4 f0 = *(const float4*)&src[i];
    float4 f1 = *(const float4*)&src[i + 4];
    unsigned short t[8] __attribute__((aligned(16))) = {
        f2bf(f0.x), f2bf(f0.y), f2bf(f0.z), f2bf(f0.w),
        f2bf(f1.x), f2bf(f1.y), f2bf(f1.z), f2bf(f1.w)};
    *(u32x4*)&dst[i] = *(const u32x4*)t;
}

// ---- prepack: Wq/Wk/Wv fp32 [H][D][DK] -> bf16 Wt [3*H*DK][D] via LDS transpose ----
// Wq is pre-scaled by log2(e)/8 so attention scores come out of QK^T ready for exp2.
__global__ void prepack_kernel(const float* __restrict__ Wq,
                               const float* __restrict__ Wk,
                               const float* __restrict__ Wv,
                               unsigned short* __restrict__ Wt) {
    __shared__ unsigned short Ts[64 * 65];
    int h = blockIdx.x, w3 = blockIdx.y, t = blockIdx.z;
    const float* src = (w3 == 0 ? Wq : (w3 == 1 ? Wk : Wv)) + h * D_ * DK_ + t * 64 * DK_;
    unsigned short* dst = Wt + (w3 * H_ + h) * DK_ * D_ + t * 64;
    const float wscale = (w3 == 0) ? 0.18033688011112042f : 1.0f;  // (1/sqrt(64)) * log2(e)
    int tid = threadIdx.x;
    for (int rep = 0; rep < 16; ++rep) {
        int idx = rep * 256 + tid;
        int dl = idx >> 6, k = idx & 63;
        Ts[k * 65 + dl] = f2bf(src[dl * 64 + k] * wscale);
    }
    __syncthreads();
    for (int rep = 0; rep < 16; ++rep) {
        int idx = rep * 256 + tid;
        int kl = idx >> 6, dl = idx & 63;
        dst[kl * D_ + dl] = Ts[kl * 65 + dl];
    }
}

// ---- merged prep: cvt(x) [4096 blocks] + cvt(Wo) [512 blocks] + prepack [768 blocks] ----
__global__ __launch_bounds__(256) void prep_kernel(const float* __restrict__ x,
                                                   const float* __restrict__ Wq,
                                                   const float* __restrict__ Wk,
                                                   const float* __restrict__ Wv,
                                                   const float* __restrict__ Wo,
                                                   unsigned short* __restrict__ xbf,
                                                   unsigned short* __restrict__ Wt,
                                                   unsigned short* __restrict__ Wobf) {
    __shared__ unsigned short Ts[64 * 65];
    const int bid = blockIdx.x;
    const int tid = threadIdx.x;
    if (bid < 4096 + 512) {
        const bool isx = bid < 4096;
        const float* src = isx ? x : Wo;
        unsigned short* dst = isx ? xbf : Wobf;
        int i = ((isx ? bid : bid - 4096) * 256 + tid) * 8;
        float4 f0 = *(const float4*)&src[i];
        float4 f1 = *(const float4*)&src[i + 4];
        unsigned short t[8] __attribute__((aligned(16))) = {
            f2bf(f0.x), f2bf(f0.y), f2bf(f0.z), f2bf(f0.w),
            f2bf(f1.x), f2bf(f1.y), f2bf(f1.z), f2bf(f1.w)};
        *(u32x4*)&dst[i] = *(const u32x4*)t;
    } else {
        const int pid = bid - 4608;
        const int h = pid & 15, w3 = (pid >> 4) % 3, t = pid / 48;
        const float* src = (w3 == 0 ? Wq : (w3 == 1 ? Wk : Wv)) + h * D_ * DK_ + t * 64 * DK_;
        unsigned short* dst = Wt + (w3 * H_ + h) * DK_ * D_ + t * 64;
        const float wscale = (w3 == 0) ? 0.18033688011112042f : 1.0f;
        for (int rep = 0; rep < 16; ++rep) {
            int idx = rep * 256 + tid;
            int dl = idx >> 6, k = idx & 63;
            Ts[k * 65 + dl] = f2bf(src[dl * 64 + k] * wscale);
        }
        __syncthreads();
        for (int rep = 0; rep < 16; ++rep) {
            int idx = rep * 256 + tid;
            int kl = idx >> 6, dl = idx & 63;
            dst[kl * D_ + dl] = Ts[kl * 65 + dl];
        }
    }
}

// ---- async stage helpers: XOR-chunk swizzle (chunk ^= row&7), linear LDS dest ----
__device__ __forceinline__ void gload16(const unsigned short* gp, unsigned short* lp) {
    __builtin_amdgcn_global_load_lds((const __attribute__((address_space(1))) unsigned int*)gp,
                                     (__attribute__((address_space(3))) unsigned int*)lp,
                                     16, 0, 0);
}

// stage one 128-row half (h=0: rows 0-127, h=1: 128-255) of a 256x64 bf16 tile; 2 instr/wave (512 thr)
__device__ __forceinline__ void stage_half(const unsigned short* __restrict__ g,
                                           unsigned short* slot, int h, int wv, int lane, int ldg) {
#pragma unroll
    for (int L = 0; L < 2; ++L) {
        int rbase = h * 128 + L * 64 + wv * 8;
        int r = rbase + (lane >> 3);
        int gc = (lane & 7) ^ ((lane >> 3) & 7);
        gload16(g + r * ldg + gc * 8, slot + rbase * 64);
    }
}

// 64 rows x 64 cols bf16 (8 KB): 1 load/thread at 512 threads
__device__ __forceinline__ void stageA_half(const unsigned short* __restrict__ g,
                                            unsigned short* lds_base, int wv, int lane, int ldg) {
    int r = wv * 8 + (lane >> 3);
    int gc = (lane & 7) ^ ((lane >> 3) & 7);
    gload16(g + r * ldg + gc * 8, lds_base + (wv * 8) * 64);
}

// 128 rows x 64 cols bf16 (16 KB): 2 loads/thread at 512 threads
__device__ __forceinline__ void stageB_half(const unsigned short* __restrict__ g,
                                            unsigned short* lds_base, int wv, int lane, int ldg) {
#pragma unroll
    for (int L = 0; L < 2; ++L) {
        int rbase = wv * 16 + L * 8;
        int r = rbase + (lane >> 3);
        int gc = (lane & 7) ^ ((lane >> 3) & 7);
        gload16(g + r * ldg + gc * 8, lds_base + rbase * 64);
    }
}

// 64 rows x 64 cols, arbitrary row stride, 256 threads (attn); 2 loads/wave
__device__ __forceinline__ void stage64_async(const unsigned short* __restrict__ g,
                                              unsigned short* lds_base, int wv, int lane, int ldg) {
#pragma unroll
    for (int it = 0; it < 2; ++it) {
        int rbase = wv * 16 + it * 8;
        int r = rbase + (lane >> 3);
        int gc = (lane & 7) ^ ((lane >> 3) & 7);
        gload16(g + r * ldg + gc * 8, lds_base + rbase * 64);
    }
}

// ---- GEMM A: C[256x256] = A[256x1024]*Bt[256x1024]^T (m201 geometry) — used for QKV ----
template <bool QKV_OUT>
__global__ __launch_bounds__(512, 2) void gemm256_kernel(const unsigned short* __restrict__ A,
                                                         const unsigned short* __restrict__ Bt,
                                                         void* __restrict__ Out,
                                                         unsigned short* __restrict__ VtOut) {
    __shared__ __align__(16) unsigned short lds[65536];  // 128 KB: A 2x16384, B 2x16384
    const int tid = threadIdx.x;
    const int wv = tid >> 6, lane = tid & 63, l15 = lane & 15, q4 = lane >> 4;
    const int wm = wv >> 2, wn = wv & 3;

    const int nwg = gridDim.x * gridDim.y;
    const int bid = blockIdx.x + blockIdx.y * gridDim.x;
    const int swz = (bid & 7) * (nwg >> 3) + (bid >> 3);
    const int bx = swz % gridDim.x, by = swz / gridDim.x;
    const int r0 = bx * 256, c0 = by * 256;

    const unsigned short* Ab = A + r0 * D_;
    const unsigned short* Bb = Bt + c0 * D_;

    f32x4 acc[8][4] = {};

    stage_half(Ab, lds, 0, wv, lane, D_);
    stage_half(Bb, lds + 32768, 0, wv, lane, D_);
    stage_half(Bb, lds + 32768, 1, wv, lane, D_);
    stage_half(Ab, lds, 1, wv, lane, D_);

    for (int j = 0; j < 16; ++j) {
        const bool nx = (j + 1 < 16);
        unsigned short* Ad = lds + (j & 1) * 16384;
        unsigned short* Bd = lds + 32768 + (j & 1) * 16384;
        unsigned short* An = lds + ((j + 1) & 1) * 16384;
        unsigned short* Bn = lds + 32768 + ((j + 1) & 1) * 16384;

        bf16x8 af[4][2], bfA[2][2], bfB[2][2];

        // phase 0: (mh0, nA); stage Ah0(j+1)
        if (nx) {
            stage_half(Ab + (j + 1) * 64, An, 0, wv, lane, D_);
            asm volatile("s_waitcnt vmcnt(6)" ::: "memory");
        } else {
            asm volatile("s_waitcnt vmcnt(4)" ::: "memory");
        }
        BAR();
#pragma unroll
        for (int kk = 0; kk < 2; ++kk) {
            const int sw = ((kk * 4 + q4) ^ (l15 & 7)) * 8;
#pragma unroll
            for (int i = 0; i < 4; ++i)
                af[i][kk] = *(const bf16x8*)&Ad[(i * 32 + wm * 16 + l15) * 64 + sw];
#pragma unroll
            for (int jf = 0; jf < 2; ++jf)
                bfA[jf][kk] = *(const bf16x8*)&Bd[(jf * 64 + wn * 16 + l15) * 64 + sw];
        }
        __builtin_amdgcn_s_setprio(1);
#pragma unroll
        for (int kk = 0; kk < 2; ++kk)
#pragma unroll
            for (int i = 0; i < 4; ++i)
#pragma unroll
                for (int jf = 0; jf < 2; ++jf)
                    acc[i][jf] = __builtin_amdgcn_mfma_f32_16x16x32_bf16(af[i][kk], bfA[jf][kk], acc[i][jf], 0, 0, 0);
        __builtin_amdgcn_s_setprio(0);

        // phase 1: (mh0, nB); stage Bh0(j+1)
        if (nx) {
            stage_half(Bb + (j + 1) * 64, Bn, 0, wv, lane, D_);
            asm volatile("s_waitcnt vmcnt(6)" ::: "memory");
        } else {
            asm volatile("s_waitcnt vmcnt(2)" ::: "memory");
        }
        BAR();
#pragma unroll
        for (int kk = 0; kk < 2; ++kk) {
            const int sw = ((kk * 4 + q4) ^ (l15 & 7)) * 8;
#pragma unroll
            for (int jf = 0; jf < 2; ++jf)
                bfB[jf][kk] = *(const bf16x8*)&Bd[((2 + jf) * 64 + wn * 16 + l15) * 64 + sw];
        }
        __builtin_amdgcn_s_setprio(1);
#pragma unroll
        for (int kk = 0; kk < 2; ++kk)
#pragma unroll
            for (int i = 0; i < 4; ++i)
#pragma unroll
                for (int jf = 0; jf < 2; ++jf)
                    acc[i][2 + jf] = __builtin_amdgcn_mfma_f32_16x16x32_bf16(af[i][kk], bfB[jf][kk], acc[i][2 + jf], 0, 0, 0);
        __builtin_amdgcn_s_setprio(0);

        // phase 2: (mh1, nB); stage Bh1(j+1)
        if (nx) {
            stage_half(Bb + (j + 1) * 64, Bn, 1, wv, lane, D_);
            asm volatile("s_waitcnt vmcnt(6)" ::: "memory");
        } else {
            asm volatile("s_waitcnt vmcnt(0)" ::: "memory");
        }
        BAR();
#pragma unroll
        for (int kk = 0; kk < 2; ++kk) {
            const int sw = ((kk * 4 + q4) ^ (l15 & 7)) * 8;
#pragma unroll
            for (int i = 0; i < 4; ++i)
                af[i][kk] = *(const bf16x8*)&Ad[(128 + i * 32 + wm * 16 + l15) * 64 + sw];
        }
        __builtin_amdgcn_s_setprio(1);
#pragma unroll
        for (int kk = 0; kk < 2; ++kk)
#pragma unroll
            for (int i = 0; i < 4; ++i)
#pragma unroll
                for (int jf = 0; jf < 2; ++jf)
                    acc[4 + i][2 + jf] = __builtin_amdgcn_mfma_f32_16x16x32_bf16(af[i][kk], bfB[jf][kk], acc[4 + i][2 + jf], 0, 0, 0);
        __builtin_amdgcn_s_setprio(0);

        // phase 3: (mh1, nA); stage Ah1(j+1); zero LDS reads
        if (nx) stage_half(Ab + (j + 1) * 64, An, 1, wv, lane, D_);
        BAR();
        __builtin_amdgcn_s_setprio(1);
#pragma unroll
        for (int kk = 0; kk < 2; ++kk)
#pragma unroll
            for (int i = 0; i < 4; ++i)
#pragma unroll
                for (int jf = 0; jf < 2; ++jf)
                    acc[4 + i][jf] = __builtin_amdgcn_mfma_f32_16x16x32_bf16(af[i][kk], bfA[jf][kk], acc[4 + i][jf], 0, 0, 0);
        __builtin_amdgcn_s_setprio(0);
    }

    __syncthreads();

    if (QKV_OUT && c0 >= 2 * D_) {
        const int b = r0 >> 11, s0 = r0 & (S_ - 1);
#pragma unroll
        for (int mh = 0; mh < 2; ++mh)
#pragma unroll
            for (int ii = 0; ii < 4; ++ii)
#pragma unroll
                for (int jf = 0; jf < 4; ++jf)
#pragma unroll
                    for (int rr = 0; rr < 4; ++rr) {
                        int cl = jf * 64 + wn * 16 + l15;
                        int rl = mh * 128 + ii * 32 + wm * 16 + q4 * 4 + rr;
                        lds[cl * 256 + (rl ^ ((cl & 7) * 8))] = f2bf(acc[mh * 4 + ii][jf][rr]);
                    }
        __syncthreads();
#pragma unroll
        for (int rep = 0; rep < 16; ++rep) {
            int idx = rep * 512 + tid;
            int col = idx >> 5, ch = idx & 31;
            u32x4 v = *(const u32x4*)&lds[col * 256 + ((ch * 8) ^ ((col & 7) * 8))];
            int gcol = c0 + col;
            int vrow = b * 1024 + (gcol & 1023);
            *(u32x4*)&VtOut[vrow * S_ + s0 + ch * 8] = v;
        }
    } else {
#pragma unroll
        for (int mh = 0; mh < 2; ++mh)
#pragma unroll
            for (int ii = 0; ii < 4; ++ii)
#pragma unroll
                for (int jf = 0; jf < 4; ++jf)
#pragma unroll
                    for (int rr = 0; rr < 4; ++rr) {
                        int grow = r0 + mh * 128 + ii * 32 + wm * 16 + q4 * 4 + rr;
                        int gcol = c0 + jf * 64 + wn * 16 + l15;
                        if (QKV_OUT) {
                            int bb = grow >> 11, s = grow & (S_ - 1);
                            int w3 = gcol >> 10, h = (gcol >> 6) & 15, dk = gcol & 63;
                            ((unsigned short*)Out)[(((w3 * B_ + bb) * H_ + h) * S_ + s) * DK_ + dk] =
                                f2bf(acc[mh * 4 + ii][jf][rr]);
                        } else {
                            ((float*)Out)[grow * D_ + gcol] = acc[mh * 4 + ii][jf][rr];
                        }
                    }
    }
}

// ---- phase MFMA cluster for GEMM B (quadrant (MH,NH), 8 ds_read + 8 MFMA) ----
template <int MH, int NH>
__device__ __forceinline__ void phase_mfma(const unsigned short* Asl, const unsigned short* Bsl,
                                           int db, int wm, int wn, int l15, int q4,
                                           f32x4 (&acc)[2][2][2][2]) {
    bf16x8 af[2][2], bf[2][2];
#pragma unroll
    for (int kk = 0; kk < 2; ++kk) {
        const int sw = ((kk * 4 + q4) ^ (l15 & 7)) * 8;
#pragma unroll
        for (int m4 = 0; m4 < 2; ++m4)
            af[m4][kk] = *(const bf16x8*)&Asl[(db + MH) * 4096 + (wm * 32 + m4 * 16 + l15) * 64 + sw];
#pragma unroll
        for (int n2 = 0; n2 < 2; ++n2)
            bf[n2][kk] = *(const bf16x8*)&Bsl[(db + NH) * 8192 + (wn * 32 + n2 * 16 + l15) * 64 + sw];
    }
    __builtin_amdgcn_s_setprio(1);
#pragma unroll
    for (int kk = 0; kk < 2; ++kk)
#pragma unroll
        for (int m4 = 0; m4 < 2; ++m4)
#pragma unroll
            for (int n2 = 0; n2 < 2; ++n2)
                acc[MH][NH][m4][n2] =
                    __builtin_amdgcn_mfma_f32_16x16x32_bf16(af[m4][kk], bf[n2][kk], acc[MH][NH][m4][n2], 0, 0, 0);
    __builtin_amdgcn_s_setprio(0);
}

// ---- GEMM B: C[128x256] = A[128x1024]*Bt[256x1024]^T — output projection, 256 blocks ----
__global__ __launch_bounds__(512) void gemm128_kernel(const unsigned short* __restrict__ A,
                                                      const unsigned short* __restrict__ Bt,
                                                      float* __restrict__ Out) {
    __shared__ __align__(16) unsigned short lds[49152];  // 96 KB: A 4x4096, B 4x8192
    unsigned short* Asl = lds;
    unsigned short* Bsl = lds + 16384;

    const int tid = threadIdx.x;
    const int wv = tid >> 6, lane = tid & 63, l15 = lane & 15, q4 = lane >> 4;
    const int wm = wv >> 2, wn = wv & 3;

    const int nwg = gridDim.x * gridDim.y;
    const int bid = blockIdx.x + blockIdx.y * gridDim.x;
    const int swz = (bid & 7) * (nwg >> 3) + (bid >> 3);
    const int bx = swz % gridDim.x, by = swz / gridDim.x;
    const int r0 = bx * 128, c0 = by * 256;

    const unsigned short* Ab = A + r0 * D_;
    const unsigned short* Bb = Bt + c0 * D_;

    f32x4 acc[2][2][2][2] = {};

    stageA_half(Ab, Asl, wv, lane, D_);
    stageB_half(Bb, Bsl, wv, lane, D_);
    stageB_half(Bb + 128 * D_, Bsl + 8192, wv, lane, D_);

    for (int j = 0; j < 16; ++j) {
        const int db = (j & 1) * 2;
        const int ndb = ((j + 1) & 1) * 2;
        const bool nx = (j + 1 < 16);

        stageA_half(Ab + 64 * D_ + j * 64, Asl + (db + 1) * 4096, wv, lane, D_);
        asm volatile("s_waitcnt vmcnt(3)" ::: "memory");
        BAR();
        phase_mfma<0, 0>(Asl, Bsl, db, wm, wn, l15, q4, acc);

        if (nx) {
            stageA_half(Ab + (j + 1) * 64, Asl + (ndb + 0) * 4096, wv, lane, D_);
            asm volatile("s_waitcnt vmcnt(2)" ::: "memory");
        } else {
            asm volatile("s_waitcnt vmcnt(1)" ::: "memory");
        }
        BAR();
        phase_mfma<0, 1>(Asl, Bsl, db, wm, wn, l15, q4, acc);

        if (nx) {
            stageB_half(Bb + (j + 1) * 64, Bsl + (ndb + 0) * 8192, wv, lane, D_);
            asm volatile("s_waitcnt vmcnt(3)" ::: "memory");
        } else {
            asm volatile("s_waitcnt vmcnt(0)" ::: "memory");
        }
        BAR();
        phase_mfma<1, 1>(Asl, Bsl, db, wm, wn, l15, q4, acc);

        if (nx) stageB_half(Bb + 128 * D_ + (j + 1) * 64, Bsl + (ndb + 1) * 8192, wv, lane, D_);
        BAR();
        phase_mfma<1, 0>(Asl, Bsl, db, wm, wn, l15, q4, acc);
    }

    __syncthreads();

#pragma unroll
    for (int mh = 0; mh < 2; ++mh)
#pragma unroll
        for (int nh = 0; nh < 2; ++nh)
#pragma unroll
            for (int m4 = 0; m4 < 2; ++m4)
#pragma unroll
                for (int n2 = 0; n2 < 2; ++n2)
#pragma unroll
                    for (int rr = 0; rr < 4; ++rr) {
                        int grow = r0 + mh * 64 + wm * 32 + m4 * 16 + q4 * 4 + rr;
                        int gcol = c0 + nh * 128 + wn * 32 + n2 * 16 + l15;
                        Out[grow * D_ + gcol] = acc[mh][nh][m4][n2][rr];
                    }
}

// ---- attn tile compute: QK^T (swapped) -> exp2 -> in-register transpose -> PV ----
__device__ __forceinline__ void attn_tile(const unsigned short* __restrict__ Kt,
                                          const unsigned short* __restrict__ Vtt,
                                          int k0, bool masked, int q0,
                                          int wv, int l15, int q4,
                                          const bf16x8 (&aq)[2][2],
                                          f32x4 (&o)[2][4], float (&l_)[2]) {
    f32x4 sa[2][4] = {};
    __builtin_amdgcn_s_setprio(1);
#pragma unroll
    for (int kk = 0; kk < 2; ++kk) {
        const int sw = ((kk * 4 + q4) ^ (l15 & 7)) * 8;
#pragma unroll
        for (int ct = 0; ct < 4; ++ct) {
            bf16x8 bk = *(const bf16x8*)&Kt[(ct * 16 + l15) * 64 + sw];
            sa[0][ct] = __builtin_amdgcn_mfma_f32_16x16x32_bf16(bk, aq[0][kk], sa[0][ct], 0, 0, 0);
            sa[1][ct] = __builtin_amdgcn_mfma_f32_16x16x32_bf16(bk, aq[1][kk], sa[1][ct], 0, 0, 0);
        }
    }
    __builtin_amdgcn_s_setprio(0);

    if (!masked) {
#pragma unroll
        for (int rt = 0; rt < 2; ++rt)
#pragma unroll
            for (int ct = 0; ct < 4; ++ct)
#pragma unroll
                for (int r = 0; r < 4; ++r)
                    sa[rt][ct][r] = __builtin_amdgcn_exp2f(sa[rt][ct][r]);
    } else {
        const int kb = k0 + q4 * 4;
#pragma unroll
        for (int rt = 0; rt < 2; ++rt) {
            const int qrow = q0 + wv * 32 + rt * 16 + l15;
#pragma unroll
            for (int ct = 0; ct < 4; ++ct)
#pragma unroll
                for (int r = 0; r < 4; ++r) {
                    float e = __builtin_amdgcn_exp2f(sa[rt][ct][r]);
                    sa[rt][ct][r] = (kb + ct * 16 + r <= qrow) ? e : 0.0f;
                }
        }
    }

#pragma unroll
    for (int rt = 0; rt < 2; ++rt)
#pragma unroll
        for (int ct = 0; ct < 4; ++ct)
            l_[rt] += (sa[rt][ct][0] + sa[rt][ct][1]) + (sa[rt][ct][2] + sa[rt][ct][3]);

    bf16x8 F[2][2];
#pragma unroll
    for (int rt = 0; rt < 2; ++rt)
#pragma unroll
        for (int kk = 0; kk < 2; ++kk) {
            u32x4 w;
#pragma unroll
            for (int u = 0; u < 2; ++u) {
                unsigned int a = cvtpk_bf16(sa[rt][2 * kk][2 * u], sa[rt][2 * kk][2 * u + 1]);
                unsigned int c = cvtpk_bf16(sa[rt][2 * kk + 1][2 * u], sa[rt][2 * kk + 1][2 * u + 1]);
                asm("v_permlane32_swap_b32 %0, %1" : "+v"(a), "+v"(c));
                asm("v_permlane16_swap_b32 %0, %1" : "+v"(a), "+v"(c));
                w[u] = a;
                w[2 + u] = c;
            }
            F[rt][kk] = *(const bf16x8*)&w;
        }

    __builtin_amdgcn_s_setprio(1);
#pragma unroll
    for (int kk = 0; kk < 2; ++kk) {
        const int sw = ((kk * 4 + q4) ^ (l15 & 7)) * 8;
#pragma unroll
        for (int cd = 0; cd < 4; ++cd) {
            bf16x8 bv = *(const bf16x8*)&Vtt[(cd * 16 + l15) * 64 + sw];
            o[0][cd] = __builtin_amdgcn_mfma_f32_16x16x32_bf16(F[0][kk], bv, o[0][cd], 0, 0, 0);
            o[1][cd] = __builtin_amdgcn_mfma_f32_16x16x32_bf16(F[1][kk], bv, o[1][cd], 0, 0, 0);
        }
    }
    __builtin_amdgcn_s_setprio(0);
}

// ---- flash attention v9: PAIRED k-tiles per iteration (128 k-cols between barriers).
//      The two tiles of a pair share one scheduling window with no barrier/wait between
//      them -> tile A's softmax/PV overlaps tile B's QK (cross-tile ILP, T15-style).
//      2 pair-sets double-buffered (64 KB); stage(p+1) right after the barrier has a
//      full pair-compute to land, so the vmcnt(0) at the next top is effectively free.
//      nk = 2j+2 is always even; the masked tiles are exactly the last pair. ----
__global__ __launch_bounds__(256) void attn_kernel(const unsigned short* __restrict__ qkv,
                                                   unsigned short* __restrict__ concat) {
    static const int J[16] = {15, 13, 11, 9, 0, 2, 4, 6, 14, 12, 10, 8, 1, 3, 5, 7};
    const int bh = blockIdx.x;
    const int b = bh >> 4, h = bh & 15;
    const int j = J[blockIdx.y];
    const int q0 = j * 128;
    const int np = j + 1;  // pairs of k-tiles (nk = 2j+2)

    const unsigned short* Qp = qkv + ((0 * B_ + b) * H_ + h) * S_ * DK_;
    const unsigned short* Kp = qkv + ((1 * B_ + b) * H_ + h) * S_ * DK_;
    const unsigned short* Vt = qkv + 2 * B_ * H_ * S_ * DK_ + (b * H_ + h) * DK_ * S_;

    __shared__ __align__(16) unsigned short Kb[2][2][64 * 64];  // [set][slot] 32 KB
    __shared__ __align__(16) unsigned short Vb[2][2][64 * 64];  // 32 KB

    const int tid = threadIdx.x;
    const int wv = tid >> 6, lane = tid & 63, l15 = lane & 15, q4 = lane >> 4;

    bf16x8 aq[2][2];
#pragma unroll
    for (int rt = 0; rt < 2; ++rt)
#pragma unroll
        for (int kk = 0; kk < 2; ++kk)
            aq[rt][kk] = *(const bf16x8*)&Qp[(q0 + wv * 32 + rt * 16 + l15) * DK_ + kk * 32 + q4 * 8];

    __syncthreads();  // reset compiler vmcnt model before counted staging

    // prologue: pair 0 -> set 0
    stage64_async(Kp, Kb[0][0], wv, lane, DK_);
    stage64_async(Vt, Vb[0][0], wv, lane, S_);
    stage64_async(Kp + 64 * DK_, Kb[0][1], wv, lane, DK_);
    stage64_async(Vt + 64, Vb[0][1], wv, lane, S_);

    f32x4 o[2][4] = {};
    float l_[2] = {0.0f, 0.0f};

    for (int p = 0; p < np; ++p) {
        asm volatile("s_waitcnt vmcnt(0)" ::: "memory");
        BAR();  // pair p staged; all waves done reading set (p+1)&1 (iter p-1)

        if (p + 1 < np) {
            const int kn = (p + 1) * 128;
            const int ns = (p + 1) & 1;
            stage64_async(Kp + kn * DK_, Kb[ns][0], wv, lane, DK_);
            stage64_async(Vt + kn, Vb[ns][0], wv, lane, S_);
            stage64_async(Kp + (kn + 64) * DK_, Kb[ns][1], wv, lane, DK_);
            stage64_async(Vt + (kn + 64), Vb[ns][1], wv, lane, S_);
        }

        const int set = p & 1;
        const bool last = (p == np - 1);
        const int k0 = p * 128;

        // tile A (k = k0 .. k0+63): always computed; masked only in last pair
        attn_tile(Kb[set][0], Vb[set][0], k0, last, q0, wv, l15, q4, aq, o, l_);
        // tile B (k = k0+64 .. k0+127): fully masked for waves 0,1 in last pair
        if (!last || wv >= 2)
            attn_tile(Kb[set][1], Vb[set][1], k0 + 64, last, q0, wv, l15, q4, aq, o, l_);
    }

    // epilogue: reduce l across the 4 lane-groups, redistribute to (q4,r) rows, normalize
#pragma unroll
    for (int rt = 0; rt < 2; ++rt) {
        float lr = l_[rt];
        lr += __shfl_xor(lr, 16);
        lr += __shfl_xor(lr, 32);
#pragma unroll
        for (int r = 0; r < 4; ++r) {
            float lfull = __shfl(lr, (lane & 48) | (q4 * 4 + r));
            float inv = 1.0f / fmaxf(lfull, 1.0e-37f);
            int row = q0 + wv * 32 + rt * 16 + q4 * 4 + r;
#pragma unroll
            for (int cd = 0; cd < 4; ++cd) {
                int col = h * DK_ + cd * 16 + l15;
                concat[(b * S_ + row) * D_ + col] = f2bf(o[rt][cd][r] * inv);
            }
        }
    }
}

extern "C" void kernel_launch(void* const* d_in, const int* in_sizes, int n_in,
                              void* d_out, int out_size, void* d_ws, size_t ws_size,
                              hipStream_t stream) {
    const float* x  = (const float*)d_in[0];
    const float* Wq = (const float*)d_in[1];
    const float* Wk = (const float*)d_in[2];
    const float* Wv = (const float*)d_in[3];
    const float* Wo = (const float*)d_in[4];

    unsigned short* qkv    = (unsigned short*)d_ws;          // 48 MB: Q,K [b][h][s][dk]; V^T [b][h][dk][s]
    unsigned short* Wt     = qkv + 3 * B_ * H_ * S_ * DK_;   //  6 MB
    unsigned short* xbf    = Wt + 3 * H_ * DK_ * D_;         // 16 MB — reused as concat after gemm<true>
    unsigned short* concat = xbf;
    unsigned short* VtOut  = qkv + 2 * B_ * H_ * S_ * DK_;

    const size_t need_shorts = (size_t)3 * B_ * H_ * S_ * DK_ + 3 * H_ * DK_ * D_ + B_ * S_ * D_ + D_ * D_;
    const bool sep = ws_size >= need_shorts * sizeof(unsigned short);

    if (sep) {
        unsigned short* Wobf = xbf + B_ * S_ * D_;
        prep_kernel<<<4096 + 512 + 768, 256, 0, stream>>>(x, Wq, Wk, Wv, Wo, xbf, Wt, Wobf);
        gemm256_kernel<true><<<dim3(32, 12), 512, 0, stream>>>(xbf, Wt, qkv, VtOut);
        attn_kernel<<<dim3(64, 16), 256, 0, stream>>>(qkv, concat);
        gemm128_kernel<<<dim3(64, 4), 512, 0, stream>>>(concat, Wobf, (float*)d_out);
    } else {
        unsigned short* Wobf = Wt;  // sequential alias: Wt dead after gemm<true>
        cvt_kernel<<<B_ * S_ * D_ / 2048, 256, 0, stream>>>(x, xbf);
        prepack_kernel<<<dim3(H_, 3, 16), 256, 0, stream>>>(Wq, Wk, Wv, Wt);
        gemm256_kernel<true><<<dim3(32, 12), 512, 0, stream>>>(xbf, Wt, qkv, VtOut);
        cvt_kernel<<<D_ * D_ / 2048, 256, 0, stream>>>(Wo, Wobf);
        attn_kernel<<<dim3(64, 16), 256, 0, stream>>>(qkv, concat);
        gemm128_kernel<<<dim3(64, 4), 512, 0, stream>>>(concat, Wobf, (float*)d_out);
    }
}